// Round 9
// baseline (1414.501 us; speedup 1.0000x reference)
//
#include <hip/hip_runtime.h>

constexpr int NUM_USERS = 100000;
constexpr int NUM_ITEMS = 50000;
constexpr int DIM = 64;
constexpr int NNZ_R = 3200000;
constexpr int NNZ_S = 2000000;
constexpr int NNZ_TOT = NNZ_R + NNZ_R + NNZ_S;   // 8.4M entries, one array

constexpr int BSH_U = 8, BROWS_U = 256;     // user/social buckets: 256 rows
constexpr int BSH_I = 7, BROWS_I = 128;     // item buckets: 128 rows
constexpr int NC_U = (NUM_USERS + BROWS_U - 1) / BROWS_U;   // 391
constexpr int NC_I = (NUM_ITEMS + BROWS_I - 1) / BROWS_I;   // 391
constexpr int NC_S = NC_U;                                  // 391
constexpr int NC = NC_U + NC_I + NC_S;                      // 1173
constexpr int NBLK = 256;                   // build blocks
constexpr int NPB = NBLK * NC;              // 300288 per-(block,bucket) counters
constexpr int CHUNK_R = NNZ_R / NBLK;       // 12500 exact
constexpr int CHUNK_S = (NNZ_S + NBLK - 1) / NBLK;  // 7813

__device__ __forceinline__ float bf2f(unsigned short u) {
    return __uint_as_float((unsigned)u << 16);
}
__device__ __forceinline__ unsigned short f2bf(float f) {   // round-to-nearest-even
    unsigned u = __float_as_uint(f);
    return (unsigned short)((u + 0x7FFFu + ((u >> 16) & 1u)) >> 16);
}

// ---- pass A: LDS histogram; store per-(block,bucket) counts (no global atomics) ----
__global__ __launch_bounds__(1024) void hist_lds(const int* __restrict__ rr,
                                                 const int* __restrict__ rc,
                                                 const int* __restrict__ sr,
                                                 int* __restrict__ cntPB /* [NBLK][NC] */) {
    __shared__ int lds[NC];
    int k = blockIdx.x, tid = threadIdx.x;
    for (int c = tid; c < NC; c += 1024) lds[c] = 0;
    __syncthreads();
    int r0 = k * CHUNK_R, r1 = r0 + CHUNK_R;
    int s0 = k * CHUNK_S, s1 = min(s0 + CHUNK_S, NNZ_S);
    for (int i = r0 + tid; i < r1; i += 1024) {
        atomicAdd(&lds[rr[i] >> BSH_U], 1);
        atomicAdd(&lds[NC_U + (rc[i] >> BSH_I)], 1);
    }
    for (int i = s0 + tid; i < s1; i += 1024)
        atomicAdd(&lds[NC_U + NC_I + (sr[i] >> BSH_U)], 1);
    __syncthreads();
    for (int c = tid; c < NC; c += 1024) cntPB[k * NC + c] = lds[c];   // contiguous 4.7KB
}

// ---- single-block exclusive scan over NPB counters in (bucket-major, block-minor)
//      logical order; physical layout is [k][c]. After this, cntPB[k*NC+c] is the
//      exact start for block k's run in bucket c, and cntPB[c] (k=0) is bucket c's base.
__global__ __launch_bounds__(1024) void exscan1(int* __restrict__ buf) {
    __shared__ int part[1024];
    int t = threadIdx.x;
    const int chunk = (NPB + 1023) >> 10;
    int lo = t * chunk, hi = min(lo + chunk, NPB);
    int s = 0;
    int c = lo >> 8, k = lo & (NBLK - 1);   // NBLK == 256
    for (int i = lo; i < hi; ++i) {
        s += buf[k * NC + c];
        if (++k == NBLK) { k = 0; ++c; }
    }
    part[t] = s;
    __syncthreads();
    for (int off = 1; off < 1024; off <<= 1) {
        int v = (t >= off) ? part[t - off] : 0;
        __syncthreads();
        part[t] += v;
        __syncthreads();
    }
    int excl = (t == 0) ? 0 : part[t - 1];
    c = lo >> 8; k = lo & (NBLK - 1);
    for (int i = lo; i < hi; ++i) {
        int idx = k * NC + c;
        int v = buf[idx];
        buf[idx] = excl;
        excl += v;
        if (++k == NBLK) { k = 0; ++c; }
    }
}

// ---- pass B: load this block's exact starts, scatter via LDS cursor bumps.
//      Runs are ~32 entries (256B) -> near-1x write amplification. Deterministic. ----
__global__ __launch_bounds__(1024) void bin_pass(const int* __restrict__ rr,
                                                 const int* __restrict__ rc,
                                                 const float* __restrict__ rv,
                                                 const int* __restrict__ sr,
                                                 const int* __restrict__ sc,
                                                 const float* __restrict__ sv,
                                                 const int* __restrict__ cntPB,
                                                 int2* __restrict__ ent) {
    __shared__ int lds[NC];
    int k = blockIdx.x, tid = threadIdx.x;
    for (int c = tid; c < NC; c += 1024) lds[c] = cntPB[k * NC + c];
    __syncthreads();
    int r0 = k * CHUNK_R, r1 = r0 + CHUNK_R;
    int s0 = k * CHUNK_S, s1 = min(s0 + CHUNK_S, NNZ_S);
    for (int i = r0 + tid; i < r1; i += 1024) {
        int r = rr[i], c = rc[i];
        int v = __float_as_int(rv[i]);
        int pu = atomicAdd(&lds[r >> BSH_U], 1);
        ent[pu] = make_int2(((r & (BROWS_U - 1)) << 17) | c, v);
        int pi = atomicAdd(&lds[NC_U + (c >> BSH_I)], 1);
        ent[pi] = make_int2(((c & (BROWS_I - 1)) << 17) | r, v);
    }
    for (int i = s0 + tid; i < s1; i += 1024) {
        int r = sr[i];
        int ps = atomicAdd(&lds[NC_U + NC_I + (r >> BSH_U)], 1);
        ent[ps] = make_int2(((r & (BROWS_U - 1)) << 17) | sc[i], __float_as_int(sv[i]));
    }
}

// ---- per-bucket counting sort (<=256 local rows): binned -> row-sorted + rowptr ----
__global__ __launch_bounds__(512) void sort_buckets(const int2* __restrict__ src,
                                                    int2* __restrict__ dst,
                                                    const int* __restrict__ cntPB,
                                                    int* __restrict__ rPu,
                                                    int* __restrict__ rPi,
                                                    int* __restrict__ rPs) {
    int gb = blockIdx.x;
    int* rowptr;
    int brows, lb, nrows;
    if (gb < NC_U)              { rowptr = rPu; brows = BROWS_U; lb = gb;               nrows = NUM_USERS; }
    else if (gb < NC_U + NC_I)  { rowptr = rPi; brows = BROWS_I; lb = gb - NC_U;        nrows = NUM_ITEMS; }
    else                        { rowptr = rPs; brows = BROWS_U; lb = gb - NC_U - NC_I; nrows = NUM_USERS; }
    int t = threadIdx.x;
    __shared__ int cnt[256];
    __shared__ int part[256];
    __shared__ int ofs[256];
    if (t < 256) cnt[t] = 0;
    __syncthreads();
    int b0 = cntPB[gb];                                  // bucket base (k=0 slot)
    int b1 = (gb == NC - 1) ? NNZ_TOT : cntPB[gb + 1];
    for (int i = b0 + t; i < b1; i += 512)
        atomicAdd(&cnt[(unsigned)src[i].x >> 17], 1);
    __syncthreads();
    if (t < 256) part[t] = cnt[t];
    __syncthreads();
    for (int off = 1; off < 256; off <<= 1) {
        int v = 0;
        if (t < 256 && t >= off) v = part[t - off];
        __syncthreads();
        if (t < 256) part[t] += v;
        __syncthreads();
    }
    if (t < 256) ofs[t] = part[t] - cnt[t];   // exclusive prefix
    __syncthreads();
    int gr = lb * brows + t;
    if (t < brows && gr < nrows) rowptr[gr] = b0 + ofs[t];
    if (gb == 0 && t == 0) {
        rPu[NUM_USERS] = NNZ_R;
        rPi[NUM_ITEMS] = 2 * NNZ_R;
        rPs[NUM_USERS] = NNZ_TOT;
    }
    __syncthreads();   // rowptr published before pass 2 mutates ofs
    for (int i = b0 + t; i < b1; i += 512) {
        int2 v = src[i];
        int lr = (unsigned)v.x >> 17;
        int pos = b0 + atomicAdd(&ofs[lr], 1);
        dst[pos] = make_int2(v.x & 0x1FFFF, v.y);
    }
}

// ---- CSR SpMM over bf16 operand rows: one row per wave, 8 gathers in flight,
//      f32 register accumulation, fused f32 weighted acc; bf16 out for next layer ----
struct SpmmOp {
    const int* rowptr;
    const int2* ent;
    const unsigned short* x;    // bf16 rows [nrows_x][64]
    unsigned short* out;        // bf16, may be nullptr (acc-only)
    float* acc;
    float w;
    int nrows;
};

__global__ __launch_bounds__(256, 4) void spmm2(SpmmOp A, SpmmOp B, int ablocks) {
    bool isA = (int)blockIdx.x < ablocks;
    SpmmOp op = isA ? A : B;
    int bid = isA ? blockIdx.x : blockIdx.x - ablocks;
    int row = bid * 4 + (threadIdx.x >> 6);
    if (row >= op.nrows) return;
    int d = threadIdx.x & 63;
    const int2* __restrict__ ent = op.ent;
    const unsigned short* __restrict__ x = op.x;
    int e = op.rowptr[row], end = op.rowptr[row + 1];
    float s0 = 0.f, s1 = 0.f, s2 = 0.f, s3 = 0.f, s4 = 0.f, s5 = 0.f, s6 = 0.f, s7 = 0.f;
    for (; e + 8 <= end; e += 8) {
        int2 e0 = ent[e],     e1 = ent[e + 1], e2 = ent[e + 2], e3 = ent[e + 3];
        int2 e4 = ent[e + 4], e5 = ent[e + 5], e6 = ent[e + 6], e7 = ent[e + 7];
        float x0 = bf2f(x[(size_t)e0.x * DIM + d]);
        float x1 = bf2f(x[(size_t)e1.x * DIM + d]);
        float x2 = bf2f(x[(size_t)e2.x * DIM + d]);
        float x3 = bf2f(x[(size_t)e3.x * DIM + d]);
        float x4 = bf2f(x[(size_t)e4.x * DIM + d]);
        float x5 = bf2f(x[(size_t)e5.x * DIM + d]);
        float x6 = bf2f(x[(size_t)e6.x * DIM + d]);
        float x7 = bf2f(x[(size_t)e7.x * DIM + d]);
        s0 += __int_as_float(e0.y) * x0;
        s1 += __int_as_float(e1.y) * x1;
        s2 += __int_as_float(e2.y) * x2;
        s3 += __int_as_float(e3.y) * x3;
        s4 += __int_as_float(e4.y) * x4;
        s5 += __int_as_float(e5.y) * x5;
        s6 += __int_as_float(e6.y) * x6;
        s7 += __int_as_float(e7.y) * x7;
    }
    for (; e < end; ++e) {
        int2 t = ent[e];
        s0 += __int_as_float(t.y) * bf2f(x[(size_t)t.x * DIM + d]);
    }
    float sum = ((s0 + s1) + (s2 + s3)) + ((s4 + s5) + (s6 + s7));
    size_t idx = (size_t)row * DIM + d;
    if (op.out) op.out[idx] = f2bf(sum);
    op.acc[idx] += op.w * sum;
}

// acc init + bf16 copies of the input embeddings (after build; aliases ent_bin region)
__global__ void init_acc(const float* __restrict__ ue, const float* __restrict__ ie,
                         float* __restrict__ accU, float* __restrict__ accI,
                         unsigned short* __restrict__ ueB, unsigned short* __restrict__ ieB,
                         int u4, int i4) {
    const float wu = 0.6f / 4.0f + 0.4f / 3.0f;
    const float wi = 0.25f;
    int i = blockIdx.x * blockDim.x + threadIdx.x;
    int st = gridDim.x * blockDim.x;
    int n4 = u4 + i4;
    for (; i < n4; i += st) {
        if (i < u4) {
            float4 v = reinterpret_cast<const float4*>(ue)[i];
            reinterpret_cast<float4*>(accU)[i] = make_float4(wu * v.x, wu * v.y, wu * v.z, wu * v.w);
            ushort4 b;
            b.x = f2bf(v.x); b.y = f2bf(v.y); b.z = f2bf(v.z); b.w = f2bf(v.w);
            reinterpret_cast<ushort4*>(ueB)[i] = b;
        } else {
            int j = i - u4;
            float4 v = reinterpret_cast<const float4*>(ie)[j];
            reinterpret_cast<float4*>(accI)[j] = make_float4(wi * v.x, wi * v.y, wi * v.z, wi * v.w);
            ushort4 b;
            b.x = f2bf(v.x); b.y = f2bf(v.y); b.z = f2bf(v.z); b.w = f2bf(v.w);
            reinterpret_cast<ushort4*>(ieB)[j] = b;
        }
    }
}

__global__ void finalize_kernel(float* __restrict__ out, int nrows) {
    int row = blockIdx.x * 4 + (threadIdx.x >> 6);
    if (row >= nrows) return;
    int d = threadIdx.x & 63;
    int idx = row * DIM + d;
    float val = out[idx];
    float sq = val * val;
    #pragma unroll
    for (int off = 32; off; off >>= 1) sq += __shfl_xor(sq, off, 64);
    out[idx] = val / fmaxf(sqrtf(sq), 1e-12f);
}

extern "C" void kernel_launch(void* const* d_in, const int* in_sizes, int n_in,
                              void* d_out, int out_size, void* d_ws, size_t ws_size,
                              hipStream_t stream) {
    const float* user_emb = (const float*)d_in[0];
    const float* item_emb = (const float*)d_in[1];
    const float* r_vals   = (const float*)d_in[2];
    const float* s_vals   = (const float*)d_in[3];
    const int*   r_rows   = (const int*)d_in[4];
    const int*   r_cols   = (const int*)d_in[5];
    const int*   s_rows   = (const int*)d_in[6];
    const int*   s_cols   = (const int*)d_in[7];

    const size_t U = (size_t)NUM_USERS * DIM;
    const size_t I = (size_t)NUM_ITEMS * DIM;

    // ---- workspace (~136.6 MB) ----
    int2* ent_sorted = (int2*)d_ws;                       // NNZ_TOT (67.2 MB), persistent
    char* region2 = (char*)(ent_sorted + NNZ_TOT);        // 67.2 MB union:
    int2* ent_bin = (int2*)region2;                       //   build-time entries
    unsigned short* ueB = (unsigned short*)region2;       //   spmm-time bf16 dense (57.6 MB)
    unsigned short* ieB = ueB + U;
    unsigned short* uA  = ieB + I;
    unsigned short* uB  = uA + U;
    unsigned short* iA  = uB + U;
    unsigned short* iB  = iA + I;
    int* cntPB = (int*)(region2 + (size_t)NNZ_TOT * 8);   // NPB counters (1.2 MB)
    int* rPu = cntPB + NPB;                               // NUM_USERS+1
    int* rPi = rPu + NUM_USERS + 1;                       // NUM_ITEMS+1
    int* rPs = rPi + NUM_ITEMS + 1;                       // NUM_USERS+1

    float* accU = (float*)d_out;
    float* accI = (float*)d_out + U;

    dim3 blk(256);

    // ---- build: per-block hist -> two-level scan -> deterministic scatter -> sort ----
    hist_lds<<<NBLK, 1024, 0, stream>>>(r_rows, r_cols, s_rows, cntPB);
    exscan1<<<1, 1024, 0, stream>>>(cntPB);
    bin_pass<<<NBLK, 1024, 0, stream>>>(r_rows, r_cols, r_vals, s_rows, s_cols, s_vals,
                                        cntPB, ent_bin);
    sort_buckets<<<NC, 512, 0, stream>>>(ent_bin, ent_sorted, cntPB, rPu, rPi, rPs);

    init_acc<<<2048, blk, 0, stream>>>(user_emb, item_emb, accU, accI, ueB, ieB,
                                       (int)(U / 4), (int)(I / 4));

    // ---- 3 bipartite layers, both directions fused per dispatch ----
    const float WU = 0.6f / 4.0f, WI = 0.25f, WS = 0.4f / 3.0f;
    int ub = (NUM_USERS + 3) / 4, ib = (NUM_ITEMS + 3) / 4;

    SpmmOp u1{rPu, ent_sorted, ieB, uA, accU, WU, NUM_USERS};
    SpmmOp i1{rPi, ent_sorted, ueB, iA, accI, WI, NUM_ITEMS};
    spmm2<<<ub + ib, blk, 0, stream>>>(u1, i1, ub);

    SpmmOp u2{rPu, ent_sorted, iA, uB, accU, WU, NUM_USERS};
    SpmmOp i2{rPi, ent_sorted, uA, iB, accI, WI, NUM_ITEMS};
    spmm2<<<ub + ib, blk, 0, stream>>>(u2, i2, ub);

    SpmmOp u3{rPu, ent_sorted, iB, nullptr, accU, WU, NUM_USERS};
    SpmmOp i3{rPi, ent_sorted, uB, nullptr, accI, WI, NUM_ITEMS};
    spmm2<<<ub + ib, blk, 0, stream>>>(u3, i3, ub);

    // ---- 2 social layers (uA dead after layer 2 -> reuse as social ping) ----
    SpmmOp so1{rPs, ent_sorted, ueB, uA, accU, WS, NUM_USERS};
    spmm2<<<ub, blk, 0, stream>>>(so1, so1, ub);
    SpmmOp so2{rPs, ent_sorted, uA, nullptr, accU, WS, NUM_USERS};
    spmm2<<<ub, blk, 0, stream>>>(so2, so2, ub);

    finalize_kernel<<<(NUM_USERS + NUM_ITEMS + 3) / 4, blk, 0, stream>>>(
        (float*)d_out, NUM_USERS + NUM_ITEMS);
}

// Round 10
// 932.488 us; speedup vs baseline: 1.5169x; 1.5169x over previous
//
#include <hip/hip_runtime.h>

constexpr int NUM_USERS = 100000;
constexpr int NUM_ITEMS = 50000;
constexpr int DIM = 64;
constexpr int NNZ_R = 3200000;
constexpr int NNZ_S = 2000000;
constexpr int NNZ_TOT = NNZ_R + NNZ_R + NNZ_S;   // 8.4M entries, one array

constexpr int BSH_U = 8, BROWS_U = 256;     // user/social buckets: 256 rows
constexpr int BSH_I = 7, BROWS_I = 128;     // item buckets: 128 rows
constexpr int NC_U = (NUM_USERS + BROWS_U - 1) / BROWS_U;   // 391
constexpr int NC_I = (NUM_ITEMS + BROWS_I - 1) / BROWS_I;   // 391
constexpr int NC_S = NC_U;                                  // 391
constexpr int NC = NC_U + NC_I + NC_S;                      // 1173
constexpr int NBLK = 512;                   // build blocks (2 per CU)
constexpr int NPB = NBLK * NC;              // 600576 per-(block,bucket) counters
constexpr int CHUNK_R = NNZ_R / NBLK;       // 6250 exact
constexpr int CHUNK_S = (NNZ_S + NBLK - 1) / NBLK;  // 3907

__device__ __forceinline__ float bf2f(unsigned short u) {
    return __uint_as_float((unsigned)u << 16);
}
__device__ __forceinline__ unsigned short f2bf(float f) {   // round-to-nearest-even
    unsigned u = __float_as_uint(f);
    return (unsigned short)((u + 0x7FFFu + ((u >> 16) & 1u)) >> 16);
}

// ---- pass A: LDS histogram; store per-(block,bucket) counts BUCKET-MAJOR ----
__global__ __launch_bounds__(1024) void hist_lds(const int* __restrict__ rr,
                                                 const int* __restrict__ rc,
                                                 const int* __restrict__ sr,
                                                 int* __restrict__ cntPB /* [NC][NBLK] */) {
    __shared__ int lds[NC];
    int k = blockIdx.x, tid = threadIdx.x;
    for (int c = tid; c < NC; c += 1024) lds[c] = 0;
    __syncthreads();
    int r0 = k * CHUNK_R, r1 = r0 + CHUNK_R;
    int s0 = k * CHUNK_S, s1 = min(s0 + CHUNK_S, NNZ_S);
    for (int i = r0 + tid; i < r1; i += 1024) {
        atomicAdd(&lds[rr[i] >> BSH_U], 1);
        atomicAdd(&lds[NC_U + (rc[i] >> BSH_I)], 1);
    }
    for (int i = s0 + tid; i < s1; i += 1024)
        atomicAdd(&lds[NC_U + NC_I + (sr[i] >> BSH_U)], 1);
    __syncthreads();
    for (int c = tid; c < NC; c += 1024) cntPB[c * NBLK + k] = lds[c];
}

// ---- per-bucket exscan over the NBLK block-counts (one block per bucket, coalesced) ----
__global__ __launch_bounds__(NBLK) void scan_bkt(int* __restrict__ cntPB,
                                                 int* __restrict__ bktTot) {
    int c = blockIdx.x, t = threadIdx.x;
    __shared__ int sh[NBLK];
    int v = cntPB[c * NBLK + t];
    sh[t] = v;
    __syncthreads();
    for (int off = 1; off < NBLK; off <<= 1) {
        int u = (t >= off) ? sh[t - off] : 0;
        __syncthreads();
        sh[t] += u;
        __syncthreads();
    }
    cntPB[c * NBLK + t] = sh[t] - v;          // exclusive prefix within bucket
    if (t == NBLK - 1) bktTot[c] = sh[t];     // bucket total
}

// ---- tiny top-level exscan over NC bucket totals (in place -> bktBase); B[NC]=total ----
__global__ __launch_bounds__(1024) void scan_top(int* __restrict__ B /* NC+1 */) {
    __shared__ int part[1024];
    int t = threadIdx.x;
    const int chunk = (NC + 1023) >> 10;
    int lo = t * chunk, hi = min(lo + chunk, NC);
    int s = 0;
    for (int i = lo; i < hi; ++i) s += B[i];
    part[t] = s;
    __syncthreads();
    for (int off = 1; off < 1024; off <<= 1) {
        int v = (t >= off) ? part[t - off] : 0;
        __syncthreads();
        part[t] += v;
        __syncthreads();
    }
    int excl = (t == 0) ? 0 : part[t - 1];
    for (int i = lo; i < hi; ++i) {
        int v = B[i];
        B[i] = excl;
        excl += v;
    }
    if (t == 1023) B[NC] = part[1023];        // == NNZ_TOT
}

// ---- pass B: exact per-(block,bucket) starts, scatter via LDS cursor bumps.
//      Deterministic; runs ~16 entries (128B) min, write amp ~1.2x. ----
__global__ __launch_bounds__(1024) void bin_pass(const int* __restrict__ rr,
                                                 const int* __restrict__ rc,
                                                 const float* __restrict__ rv,
                                                 const int* __restrict__ sr,
                                                 const int* __restrict__ sc,
                                                 const float* __restrict__ sv,
                                                 const int* __restrict__ cntPB,
                                                 const int* __restrict__ bktBase,
                                                 int2* __restrict__ ent) {
    __shared__ int lds[NC];
    int k = blockIdx.x, tid = threadIdx.x;
    for (int c = tid; c < NC; c += 1024)
        lds[c] = bktBase[c] + cntPB[c * NBLK + k];
    __syncthreads();
    int r0 = k * CHUNK_R, r1 = r0 + CHUNK_R;
    int s0 = k * CHUNK_S, s1 = min(s0 + CHUNK_S, NNZ_S);
    for (int i = r0 + tid; i < r1; i += 1024) {
        int r = rr[i], c = rc[i];
        int v = __float_as_int(rv[i]);
        int pu = atomicAdd(&lds[r >> BSH_U], 1);
        ent[pu] = make_int2(((r & (BROWS_U - 1)) << 17) | c, v);
        int pi = atomicAdd(&lds[NC_U + (c >> BSH_I)], 1);
        ent[pi] = make_int2(((c & (BROWS_I - 1)) << 17) | r, v);
    }
    for (int i = s0 + tid; i < s1; i += 1024) {
        int r = sr[i];
        int ps = atomicAdd(&lds[NC_U + NC_I + (r >> BSH_U)], 1);
        ent[ps] = make_int2(((r & (BROWS_U - 1)) << 17) | sc[i], __float_as_int(sv[i]));
    }
}

// ---- per-bucket counting sort (<=256 local rows): binned -> row-sorted + rowptr ----
__global__ __launch_bounds__(512) void sort_buckets(const int2* __restrict__ src,
                                                    int2* __restrict__ dst,
                                                    const int* __restrict__ bktBase,
                                                    int* __restrict__ rPu,
                                                    int* __restrict__ rPi,
                                                    int* __restrict__ rPs) {
    int gb = blockIdx.x;
    int* rowptr;
    int brows, lb, nrows;
    if (gb < NC_U)              { rowptr = rPu; brows = BROWS_U; lb = gb;               nrows = NUM_USERS; }
    else if (gb < NC_U + NC_I)  { rowptr = rPi; brows = BROWS_I; lb = gb - NC_U;        nrows = NUM_ITEMS; }
    else                        { rowptr = rPs; brows = BROWS_U; lb = gb - NC_U - NC_I; nrows = NUM_USERS; }
    int t = threadIdx.x;
    __shared__ int cnt[256];
    __shared__ int part[256];
    __shared__ int ofs[256];
    if (t < 256) cnt[t] = 0;
    __syncthreads();
    int b0 = bktBase[gb], b1 = bktBase[gb + 1];
    for (int i = b0 + t; i < b1; i += 512)
        atomicAdd(&cnt[(unsigned)src[i].x >> 17], 1);
    __syncthreads();
    if (t < 256) part[t] = cnt[t];
    __syncthreads();
    for (int off = 1; off < 256; off <<= 1) {
        int v = 0;
        if (t < 256 && t >= off) v = part[t - off];
        __syncthreads();
        if (t < 256) part[t] += v;
        __syncthreads();
    }
    if (t < 256) ofs[t] = part[t] - cnt[t];   // exclusive prefix
    __syncthreads();
    int gr = lb * brows + t;
    if (t < brows && gr < nrows) rowptr[gr] = b0 + ofs[t];
    if (gb == 0 && t == 0) {
        rPu[NUM_USERS] = NNZ_R;
        rPi[NUM_ITEMS] = 2 * NNZ_R;
        rPs[NUM_USERS] = NNZ_TOT;
    }
    __syncthreads();   // rowptr published before pass 2 mutates ofs
    for (int i = b0 + t; i < b1; i += 512) {
        int2 v = src[i];
        int lr = (unsigned)v.x >> 17;
        int pos = b0 + atomicAdd(&ofs[lr], 1);
        dst[pos] = make_int2(v.x & 0x1FFFF, v.y);
    }
}

// ---- CSR SpMM over bf16 operand rows: one row per wave, 8 gathers in flight,
//      f32 register accumulation, fused f32 weighted acc; bf16 out for next layer ----
struct SpmmOp {
    const int* rowptr;
    const int2* ent;
    const unsigned short* x;    // bf16 rows [nrows_x][64]
    unsigned short* out;        // bf16, may be nullptr (acc-only)
    float* acc;
    float w;
    int nrows;
};

__global__ __launch_bounds__(256, 4) void spmm2(SpmmOp A, SpmmOp B, int ablocks) {
    bool isA = (int)blockIdx.x < ablocks;
    SpmmOp op = isA ? A : B;
    int bid = isA ? blockIdx.x : blockIdx.x - ablocks;
    int row = bid * 4 + (threadIdx.x >> 6);
    if (row >= op.nrows) return;
    int d = threadIdx.x & 63;
    const int2* __restrict__ ent = op.ent;
    const unsigned short* __restrict__ x = op.x;
    int e = op.rowptr[row], end = op.rowptr[row + 1];
    float s0 = 0.f, s1 = 0.f, s2 = 0.f, s3 = 0.f, s4 = 0.f, s5 = 0.f, s6 = 0.f, s7 = 0.f;
    for (; e + 8 <= end; e += 8) {
        int2 e0 = ent[e],     e1 = ent[e + 1], e2 = ent[e + 2], e3 = ent[e + 3];
        int2 e4 = ent[e + 4], e5 = ent[e + 5], e6 = ent[e + 6], e7 = ent[e + 7];
        float x0 = bf2f(x[(size_t)e0.x * DIM + d]);
        float x1 = bf2f(x[(size_t)e1.x * DIM + d]);
        float x2 = bf2f(x[(size_t)e2.x * DIM + d]);
        float x3 = bf2f(x[(size_t)e3.x * DIM + d]);
        float x4 = bf2f(x[(size_t)e4.x * DIM + d]);
        float x5 = bf2f(x[(size_t)e5.x * DIM + d]);
        float x6 = bf2f(x[(size_t)e6.x * DIM + d]);
        float x7 = bf2f(x[(size_t)e7.x * DIM + d]);
        s0 += __int_as_float(e0.y) * x0;
        s1 += __int_as_float(e1.y) * x1;
        s2 += __int_as_float(e2.y) * x2;
        s3 += __int_as_float(e3.y) * x3;
        s4 += __int_as_float(e4.y) * x4;
        s5 += __int_as_float(e5.y) * x5;
        s6 += __int_as_float(e6.y) * x6;
        s7 += __int_as_float(e7.y) * x7;
    }
    for (; e < end; ++e) {
        int2 t = ent[e];
        s0 += __int_as_float(t.y) * bf2f(x[(size_t)t.x * DIM + d]);
    }
    float sum = ((s0 + s1) + (s2 + s3)) + ((s4 + s5) + (s6 + s7));
    size_t idx = (size_t)row * DIM + d;
    if (op.out) op.out[idx] = f2bf(sum);
    op.acc[idx] += op.w * sum;
}

// acc init + bf16 copies of the input embeddings (after build; aliases ent_bin region)
__global__ void init_acc(const float* __restrict__ ue, const float* __restrict__ ie,
                         float* __restrict__ accU, float* __restrict__ accI,
                         unsigned short* __restrict__ ueB, unsigned short* __restrict__ ieB,
                         int u4, int i4) {
    const float wu = 0.6f / 4.0f + 0.4f / 3.0f;
    const float wi = 0.25f;
    int i = blockIdx.x * blockDim.x + threadIdx.x;
    int st = gridDim.x * blockDim.x;
    int n4 = u4 + i4;
    for (; i < n4; i += st) {
        if (i < u4) {
            float4 v = reinterpret_cast<const float4*>(ue)[i];
            reinterpret_cast<float4*>(accU)[i] = make_float4(wu * v.x, wu * v.y, wu * v.z, wu * v.w);
            ushort4 b;
            b.x = f2bf(v.x); b.y = f2bf(v.y); b.z = f2bf(v.z); b.w = f2bf(v.w);
            reinterpret_cast<ushort4*>(ueB)[i] = b;
        } else {
            int j = i - u4;
            float4 v = reinterpret_cast<const float4*>(ie)[j];
            reinterpret_cast<float4*>(accI)[j] = make_float4(wi * v.x, wi * v.y, wi * v.z, wi * v.w);
            ushort4 b;
            b.x = f2bf(v.x); b.y = f2bf(v.y); b.z = f2bf(v.z); b.w = f2bf(v.w);
            reinterpret_cast<ushort4*>(ieB)[j] = b;
        }
    }
}

__global__ void finalize_kernel(float* __restrict__ out, int nrows) {
    int row = blockIdx.x * 4 + (threadIdx.x >> 6);
    if (row >= nrows) return;
    int d = threadIdx.x & 63;
    int idx = row * DIM + d;
    float val = out[idx];
    float sq = val * val;
    #pragma unroll
    for (int off = 32; off; off >>= 1) sq += __shfl_xor(sq, off, 64);
    out[idx] = val / fmaxf(sqrtf(sq), 1e-12f);
}

extern "C" void kernel_launch(void* const* d_in, const int* in_sizes, int n_in,
                              void* d_out, int out_size, void* d_ws, size_t ws_size,
                              hipStream_t stream) {
    const float* user_emb = (const float*)d_in[0];
    const float* item_emb = (const float*)d_in[1];
    const float* r_vals   = (const float*)d_in[2];
    const float* s_vals   = (const float*)d_in[3];
    const int*   r_rows   = (const int*)d_in[4];
    const int*   r_cols   = (const int*)d_in[5];
    const int*   s_rows   = (const int*)d_in[6];
    const int*   s_cols   = (const int*)d_in[7];

    const size_t U = (size_t)NUM_USERS * DIM;
    const size_t I = (size_t)NUM_ITEMS * DIM;

    // ---- workspace (~138 MB) ----
    int2* ent_sorted = (int2*)d_ws;                       // NNZ_TOT (67.2 MB), persistent
    char* region2 = (char*)(ent_sorted + NNZ_TOT);        // 67.2 MB union:
    int2* ent_bin = (int2*)region2;                       //   build-time entries
    unsigned short* ueB = (unsigned short*)region2;       //   spmm-time bf16 dense (57.6 MB)
    unsigned short* ieB = ueB + U;
    unsigned short* uA  = ieB + I;
    unsigned short* uB  = uA + U;
    unsigned short* iA  = uB + U;
    unsigned short* iB  = iA + I;
    int* cntPB   = (int*)(region2 + (size_t)NNZ_TOT * 8); // [NC][NBLK] (2.4 MB)
    int* bktBase = cntPB + NPB;                           // NC+1 (totals -> bases)
    int* rPu = bktBase + NC + 1;                          // NUM_USERS+1
    int* rPi = rPu + NUM_USERS + 1;                       // NUM_ITEMS+1
    int* rPs = rPi + NUM_ITEMS + 1;                       // NUM_USERS+1

    float* accU = (float*)d_out;
    float* accI = (float*)d_out + U;

    dim3 blk(256);

    // ---- build: hist -> per-bucket scan -> top scan -> deterministic scatter -> sort ----
    hist_lds<<<NBLK, 1024, 0, stream>>>(r_rows, r_cols, s_rows, cntPB);
    scan_bkt<<<NC, NBLK, 0, stream>>>(cntPB, bktBase);
    scan_top<<<1, 1024, 0, stream>>>(bktBase);
    bin_pass<<<NBLK, 1024, 0, stream>>>(r_rows, r_cols, r_vals, s_rows, s_cols, s_vals,
                                        cntPB, bktBase, ent_bin);
    sort_buckets<<<NC, 512, 0, stream>>>(ent_bin, ent_sorted, bktBase, rPu, rPi, rPs);

    init_acc<<<2048, blk, 0, stream>>>(user_emb, item_emb, accU, accI, ueB, ieB,
                                       (int)(U / 4), (int)(I / 4));

    // ---- 3 bipartite layers, both directions fused per dispatch ----
    const float WU = 0.6f / 4.0f, WI = 0.25f, WS = 0.4f / 3.0f;
    int ub = (NUM_USERS + 3) / 4, ib = (NUM_ITEMS + 3) / 4;

    SpmmOp u1{rPu, ent_sorted, ieB, uA, accU, WU, NUM_USERS};
    SpmmOp i1{rPi, ent_sorted, ueB, iA, accI, WI, NUM_ITEMS};
    spmm2<<<ub + ib, blk, 0, stream>>>(u1, i1, ub);

    SpmmOp u2{rPu, ent_sorted, iA, uB, accU, WU, NUM_USERS};
    SpmmOp i2{rPi, ent_sorted, uA, iB, accI, WI, NUM_ITEMS};
    spmm2<<<ub + ib, blk, 0, stream>>>(u2, i2, ub);

    SpmmOp u3{rPu, ent_sorted, iB, nullptr, accU, WU, NUM_USERS};
    SpmmOp i3{rPi, ent_sorted, uB, nullptr, accI, WI, NUM_ITEMS};
    spmm2<<<ub + ib, blk, 0, stream>>>(u3, i3, ub);

    // ---- 2 social layers (uA dead after layer 2 -> reuse as social ping) ----
    SpmmOp so1{rPs, ent_sorted, ueB, uA, accU, WS, NUM_USERS};
    spmm2<<<ub, blk, 0, stream>>>(so1, so1, ub);
    SpmmOp so2{rPs, ent_sorted, uA, nullptr, accU, WS, NUM_USERS};
    spmm2<<<ub, blk, 0, stream>>>(so2, so2, ub);

    finalize_kernel<<<(NUM_USERS + NUM_ITEMS + 3) / 4, blk, 0, stream>>>(
        (float*)d_out, NUM_USERS + NUM_ITEMS);
}